// Round 9
// baseline (227.449 us; speedup 1.0000x reference)
//
#include <hip/hip_runtime.h>
#include <math.h>
#include <stdint.h>

#define B 8
#define C 64
#define H 256
#define W 256
#define NPLANE 16            // 2 inputs x 8 batches
#define PSZ (H * W)          // 65536

// workspace layout
#define OFF_WC    256                        // 2*64*9 f64 = 9216 B
#define OFF_BIAS  9728                       // 2 f64
#define OFF_F     16384                      // 16*PSZ f64 = 8388608 B

// ---------------------------------------------------------------------------
// prep: fold pointwise weight into depthwise taps (f64), fold biases.
// ---------------------------------------------------------------------------
__global__ void prep_kernel(const float* __restrict__ dw_w0, const float* __restrict__ dw_b0,
                            const float* __restrict__ pw_w0, const float* __restrict__ pw_b0,
                            const float* __restrict__ dw_w1, const float* __restrict__ dw_b1,
                            const float* __restrict__ pw_w1, const float* __restrict__ pw_b1,
                            double* __restrict__ wc, double* __restrict__ bias)
{
    int t = threadIdx.x;            // 0..127
    int which = t >> 6, c = t & 63;
    const float* dw = which ? dw_w1 : dw_w0;
    const float* pw = which ? pw_w1 : pw_w0;
    double p = (double)pw[c];
    #pragma unroll
    for (int k = 0; k < 9; ++k)
        wc[(which * 64 + c) * 9 + k] = p * (double)dw[c * 9 + k];
    if (c == 0) {
        const float* dwb = which ? dw_b1 : dw_b0;
        const float* pwb = which ? pw_b1 : pw_b0;
        double acc = (double)pwb[0];
        for (int cc = 0; cc < 64; ++cc) acc += (double)pw[cc] * (double)dwb[cc];
        bias[which] = acc;
    }
}

// ---------------------------------------------------------------------------
// per-wave accumulation over NCH channels; plain register loads, TLP hides
// latency (24 waves/CU). JLO/JHI skip invalid halo rows at image edges
// (loads use clamped rows and are simply unused there).
// ---------------------------------------------------------------------------
template<int JLO, int JHI>
__device__ __forceinline__ void accum_channels(
    const float* __restrict__ xc0,   // plane base + cbase*PSZ + lane*4
    const double* __restrict__ w9g,  // folded weights for channel cbase
    const int gy[6], int lane, double acc[4][4])
{
    #pragma unroll 1
    for (int cc = 0; cc < 8; ++cc) {
        const float* xc = xc0 + (size_t)cc * PSZ;

        float4 rv[6];
        #pragma unroll
        for (int j = 0; j < 6; ++j)
            rv[j] = *(const float4*)(xc + gy[j]);

        double wl[9];
        #pragma unroll
        for (int t = 0; t < 9; ++t) wl[t] = w9g[cc * 9 + t];

        #pragma unroll
        for (int j = 0; j < 6; ++j) {
            if (j < JLO || j > JHI) continue;
            float lf = __shfl_up(rv[j].w, 1);
            float rf = __shfl_down(rv[j].x, 1);
            if (lane == 0)  lf = 0.0f;
            if (lane == 63) rf = 0.0f;
            double dd[6] = {(double)lf, (double)rv[j].x, (double)rv[j].y,
                            (double)rv[j].z, (double)rv[j].w, (double)rf};
            #pragma unroll
            for (int i = 0; i < 3; ++i) {
                const int o = j - i;                 // output row
                if (o >= 0 && o < 4) {
                    double wa = wl[3 * i], wb = wl[3 * i + 1], wcv = wl[3 * i + 2];
                    #pragma unroll
                    for (int k = 0; k < 4; ++k)
                        acc[o][k] += wa * dd[k] + wb * dd[k + 1] + wcv * dd[k + 2];
                }
            }
        }
    }
}

// ---------------------------------------------------------------------------
// score: block = (plane, 4-row band), 512 threads = 8 waves x 8 channels.
// Occupancy-first: launch_bounds(512,6) caps VGPR at ~85 -> 3 blocks/CU
// = 24 waves/CU; latency hidden by TLP, not per-wave MLP.
// Reduction is a 2-stage tree so LDS high-water stays 32 KB.
// f64 end-to-end so the argmax selection matches the f64 numpy reference.
// ---------------------------------------------------------------------------
__global__ __launch_bounds__(512, 6) void score_band_kernel(
    const float* __restrict__ x0, const float* __restrict__ x1,
    const double* __restrict__ wc, const double* __restrict__ bias,
    double* __restrict__ f)
{
    __shared__ double sred[4][4][4][64];   // [slot][row][k][lane] = 32 KiB

    // XCD-bijective swizzle: adjacent bands land on the same XCD (L2 halo reuse).
    const int n     = blockIdx.x;
    const int task  = (n & 7) * 128 + (n >> 3);
    const int plane = task >> 6;         // 0..15
    const int band  = task & 63;         // 0..63
    const int which = plane >> 3;
    const int b     = plane & 7;
    const int y0    = band * 4;

    const int tid  = threadIdx.x;
    const int w    = tid >> 6;           // wave 0..7
    const int lane = tid & 63;

    const float*  xp = (which ? x1 : x0) + (size_t)b * C * PSZ;
    const double* wp = wc + which * (C * 9);
    const int cbase  = w * 8;

    int gy[6];
    #pragma unroll
    for (int j = 0; j < 6; ++j) {
        int r = y0 - 1 + j;
        r = r < 0 ? 0 : (r > H - 1 ? H - 1 : r);   // clamped; edge rows skipped in compute
        gy[j] = r * W;
    }

    const float*  xc0 = xp + (size_t)cbase * PSZ + lane * 4;
    const double* w9g = wp + cbase * 9;

    double acc[4][4] = {};   // [out-row][px]

    if (band == 0)       accum_channels<1, 5>(xc0, w9g, gy, lane, acc);
    else if (band == 63) accum_channels<0, 4>(xc0, w9g, gy, lane, acc);
    else                 accum_channels<0, 5>(xc0, w9g, gy, lane, acc);

    // ---- 2-stage deterministic tree reduction (8 -> 4 -> 1) ----
    if (w >= 4) {
        #pragma unroll
        for (int o = 0; o < 4; ++o)
            #pragma unroll
            for (int k = 0; k < 4; ++k)
                sred[w - 4][o][k][lane] = acc[o][k];
    }
    __syncthreads();
    if (w < 4) {
        #pragma unroll
        for (int o = 0; o < 4; ++o)
            #pragma unroll
            for (int k = 0; k < 4; ++k)
                acc[o][k] += sred[w][o][k][lane];
    }
    __syncthreads();
    if (w < 4) {
        #pragma unroll
        for (int o = 0; o < 4; ++o)
            #pragma unroll
            for (int k = 0; k < 4; ++k)
                sred[w][o][k][lane] = acc[o][k];
    }
    __syncthreads();

    // final: 1024 outputs, 512 threads, fixed summation order (deterministic)
    const double bv = bias[which];
    double* fpl = f + (size_t)plane * PSZ + (size_t)y0 * W;
    #pragma unroll
    for (int it = 0; it < 2; ++it) {
        int idx = tid + it * 512;
        int row = idx >> 8;
        int px  = idx & 255;
        int lr  = px >> 2, kr = px & 3;
        double s = sred[0][row][kr][lr] + sred[1][row][kr][lr]
                 + sred[2][row][kr][lr] + sred[3][row][kr][lr] + bv;
        fpl[row * W + px] = 1.0 + 1.0 / (1.0 + exp(-s));
    }
}

// ---------------------------------------------------------------------------
// Selection. block = one (b,y) row; 256 threads = 64 float4-cols x 4 channel
// groups. f-row values live in registers, reused over 16 channels.
// ---------------------------------------------------------------------------
__global__ __launch_bounds__(256) void select_kernel(
    const float*  __restrict__ x0,
    const float*  __restrict__ x1,
    const double* __restrict__ f0,
    const double* __restrict__ f1,
    float* __restrict__ out,
    unsigned int* __restrict__ count1)
{
    const int by = blockIdx.x;        // 0 .. B*H-1
    const int b  = by >> 8;
    const int y  = by & (H - 1);
    const int tx = threadIdx.x & 63;
    const int tc = threadIdx.x >> 6;

    const size_t plane = (size_t)b * H * W + (size_t)y * W + (size_t)tx * 4;
    double g0[4], g1[4];
    #pragma unroll
    for (int j = 0; j < 4; ++j) { g0[j] = f0[plane + j]; g1[j] = f1[plane + j]; }

    const size_t rowbase = (size_t)b * C * H * W + (size_t)y * W + (size_t)tx * 4;

    unsigned int cnt = 0;
    for (int ci = tc; ci < C; ci += 4) {
        size_t off = rowbase + (size_t)ci * H * W;
        float4 a  = *(const float4*)(x0 + off);
        float4 bb = *(const float4*)(x1 + off);
        float4 r;
        { double w0=(double)a.x*g0[0], w1=(double)bb.x*g1[0]; bool s1=(w1>w0); cnt+=s1; r.x=s1?bb.x:a.x; }
        { double w0=(double)a.y*g0[1], w1=(double)bb.y*g1[1]; bool s1=(w1>w0); cnt+=s1; r.y=s1?bb.y:a.y; }
        { double w0=(double)a.z*g0[2], w1=(double)bb.z*g1[2]; bool s1=(w1>w0); cnt+=s1; r.z=s1?bb.z:a.z; }
        { double w0=(double)a.w*g0[3], w1=(double)bb.w*g1[3]; bool s1=(w1>w0); cnt+=s1; r.w=s1?bb.w:a.w; }
        *(float4*)(out + off) = r;
    }

    __shared__ unsigned int blk;
    if (threadIdx.x == 0) blk = 0;
    __syncthreads();
    atomicAdd(&blk, cnt);
    __syncthreads();
    if (threadIdx.x == 0) atomicAdd(count1, blk);
}

__global__ void finalize_kernel(const unsigned int* __restrict__ count1,
                                float* __restrict__ out_p)
{
    const double N = (double)B * C * H * W;
    double c1 = (double)(*count1);
    out_p[0] = (float)((N - c1) / N);
    out_p[1] = (float)(c1 / N);
}

extern "C" void kernel_launch(void* const* d_in, const int* in_sizes, int n_in,
                              void* d_out, int out_size, void* d_ws, size_t ws_size,
                              hipStream_t stream) {
    const float* x0    = (const float*)d_in[0];
    const float* x1    = (const float*)d_in[1];
    const float* dw_w0 = (const float*)d_in[2];
    const float* dw_b0 = (const float*)d_in[3];
    const float* pw_w0 = (const float*)d_in[4];
    const float* pw_b0 = (const float*)d_in[5];
    const float* dw_w1 = (const float*)d_in[6];
    const float* dw_b1 = (const float*)d_in[7];
    const float* pw_w1 = (const float*)d_in[8];
    const float* pw_b1 = (const float*)d_in[9];
    float* out = (float*)d_out;

    unsigned int* cnt  = (unsigned int*)d_ws;
    double*       wc   = (double*)((char*)d_ws + OFF_WC);
    double*       bias = (double*)((char*)d_ws + OFF_BIAS);
    double*       f    = (double*)((char*)d_ws + OFF_F);
    double*       f0   = f;                       // planes 0..7  (input 0)
    double*       f1   = f + (size_t)8 * PSZ;     // planes 8..15 (input 1)

    (void)hipMemsetAsync(d_ws, 0, 256, stream);

    prep_kernel<<<1, 128, 0, stream>>>(dw_w0, dw_b0, pw_w0, pw_b0,
                                       dw_w1, dw_b1, pw_w1, pw_b1, wc, bias);

    score_band_kernel<<<NPLANE * (H / 4), 512, 0, stream>>>(x0, x1, wc, bias, f);

    select_kernel<<<B * H, 256, 0, stream>>>(x0, x1, f0, f1, out, cnt);

    finalize_kernel<<<1, 1, 0, stream>>>(cnt, out + (size_t)B * C * H * W);
}

// Round 10
// 146.025 us; speedup vs baseline: 1.5576x; 1.5576x over previous
//
#include <hip/hip_runtime.h>
#include <math.h>
#include <stdint.h>

#define B 8
#define C 64
#define H 256
#define W 256
#define NPLANE 16            // 2 inputs x 8 batches
#define PSZ (H * W)          // 65536

// workspace layout
#define OFF_WC    256                        // 2*64*9 f64 = 9216 B
#define OFF_BIAS  9728                       // 2 f64
#define OFF_F     16384                      // 16*PSZ f64 = 8388608 B

// ---------------------------------------------------------------------------
// prep: fold pointwise weight into depthwise taps (f64), fold biases.
// ---------------------------------------------------------------------------
__global__ void prep_kernel(const float* __restrict__ dw_w0, const float* __restrict__ dw_b0,
                            const float* __restrict__ pw_w0, const float* __restrict__ pw_b0,
                            const float* __restrict__ dw_w1, const float* __restrict__ dw_b1,
                            const float* __restrict__ pw_w1, const float* __restrict__ pw_b1,
                            double* __restrict__ wc, double* __restrict__ bias)
{
    int t = threadIdx.x;            // 0..127
    int which = t >> 6, c = t & 63;
    const float* dw = which ? dw_w1 : dw_w0;
    const float* pw = which ? pw_w1 : pw_w0;
    double p = (double)pw[c];
    #pragma unroll
    for (int k = 0; k < 9; ++k)
        wc[(which * 64 + c) * 9 + k] = p * (double)dw[c * 9 + k];
    if (c == 0) {
        const float* dwb = which ? dw_b1 : dw_b0;
        const float* pwb = which ? pw_b1 : pw_b0;
        double acc = (double)pwb[0];
        for (int cc = 0; cc < 64; ++cc) acc += (double)pw[cc] * (double)dwb[cc];
        bias[which] = acc;
    }
}

// ---------------------------------------------------------------------------
// 16-channel accumulation for a 2-row band. Plain float4 loads (4 rows in
// flight), weights scalarized to SGPRs via readfirstlane'd uniform index.
// JLO/JHI skip invalid halo rows at image top/bottom.
// ---------------------------------------------------------------------------
template<int JLO, int JHI>
__device__ __forceinline__ void accum16(
    const float* __restrict__ xb,   // plane base + lane*4
    const double* __restrict__ wp,  // folded weights for this input
    int cb,                         // uniform channel base (readfirstlane'd)
    int g0, int g1, int g2, int g3, // uniform row offsets (elements)
    int lane, double acc[2][4])
{
    #pragma unroll 1
    for (int cc = 0; cc < 16; ++cc) {
        const float* xc = xb + (size_t)(cb + cc) * PSZ;
        float4 rv0 = *(const float4*)(xc + g0);
        float4 rv1 = *(const float4*)(xc + g1);
        float4 rv2 = *(const float4*)(xc + g2);
        float4 rv3 = *(const float4*)(xc + g3);

        const double* w9 = wp + (size_t)(cb + cc) * 9;   // uniform -> s_load

#define ROW(j, RV)                                                             \
        if (j >= JLO && j <= JHI) {                                            \
            float lf = __shfl_up(RV.w, 1);                                     \
            float rf = __shfl_down(RV.x, 1);                                   \
            if (lane == 0)  lf = 0.0f;                                         \
            if (lane == 63) rf = 0.0f;                                         \
            double d0 = (double)lf,   d1 = (double)RV.x, d2 = (double)RV.y;    \
            double d3 = (double)RV.z, d4 = (double)RV.w, d5 = (double)rf;      \
            _Pragma("unroll")                                                  \
            for (int i = 0; i < 3; ++i) {                                      \
                const int o = j - i;                                           \
                if (o >= 0 && o < 2) {                                         \
                    double wa = w9[3 * i], wb = w9[3 * i + 1],                 \
                           wcv = w9[3 * i + 2];                                \
                    acc[o][0] += wa * d0 + wb * d1 + wcv * d2;                 \
                    acc[o][1] += wa * d1 + wb * d2 + wcv * d3;                 \
                    acc[o][2] += wa * d2 + wb * d3 + wcv * d4;                 \
                    acc[o][3] += wa * d3 + wb * d4 + wcv * d5;                 \
                }                                                              \
            }                                                                  \
        }
        ROW(0, rv0) ROW(1, rv1) ROW(2, rv2) ROW(3, rv3)
#undef ROW
    }
}

// ---------------------------------------------------------------------------
// score: block = (plane, 2-row band), 256 threads = 4 waves x 16 channels.
// Lean VGPR (acc[2][4] + 4 row loads, weights in SGPRs), small LDS (16 KB),
// 2048 blocks -> occupancy from block count, not per-wave pipelining.
// f64 end-to-end so the argmax selection matches the f64 numpy reference.
// ---------------------------------------------------------------------------
__global__ __launch_bounds__(256) void score2row_kernel(
    const float* __restrict__ x0, const float* __restrict__ x1,
    const double* __restrict__ wc, const double* __restrict__ bias,
    double* __restrict__ f)
{
    __shared__ double sred[4][2][4][64];   // [slot][row][k][lane] = 16 KiB

    // XCD-bijective swizzle: consecutive tasks (adjacent bands) on one XCD.
    const int n     = blockIdx.x;                    // 0..2047
    const int task  = (n & 7) * 256 + (n >> 3);
    const int plane = task >> 7;         // 0..15
    const int band  = task & 127;        // 0..127
    const int which = plane >> 3;
    const int b     = plane & 7;
    const int y0    = band * 2;

    const int tid  = threadIdx.x;
    const int w    = tid >> 6;           // wave 0..3
    const int lane = tid & 63;

    const float*  xp = (which ? x1 : x0) + (size_t)b * C * PSZ;
    const double* wp = wc + which * (C * 9);
    const int cb = __builtin_amdgcn_readfirstlane(w * 16);

    // uniform clamped row offsets (elements); invalid rows skipped in compute
    int g0, g1, g2, g3;
    {
        int r0 = y0 - 1, r1 = y0, r2 = y0 + 1, r3 = y0 + 2;
        r0 = r0 < 0 ? 0 : r0;
        r3 = r3 > H - 1 ? H - 1 : r3;
        g0 = r0 * W; g1 = r1 * W; g2 = r2 * W; g3 = r3 * W;
    }

    const float* xb = xp + lane * 4;
    double acc[2][4] = {};

    if (band == 0)        accum16<1, 3>(xb, wp, cb, g0, g1, g2, g3, lane, acc);
    else if (band == 127) accum16<0, 2>(xb, wp, cb, g0, g1, g2, g3, lane, acc);
    else                  accum16<0, 3>(xb, wp, cb, g0, g1, g2, g3, lane, acc);

    // dump all 4 waves' partials (symmetric, no divergence), then combine.
    #pragma unroll
    for (int o = 0; o < 2; ++o)
        #pragma unroll
        for (int k = 0; k < 4; ++k)
            sred[w][o][k][lane] = acc[o][k];
    __syncthreads();

    const double bv = bias[which];
    double* fpl = f + (size_t)plane * PSZ + (size_t)y0 * W;
    #pragma unroll
    for (int it = 0; it < 2; ++it) {
        int idx = it * 256 + tid;       // 0..511
        int row = idx >> 8;
        int px  = idx & 255;
        int k   = px & 3, l = px >> 2;
        double s = sred[0][row][k][l] + sred[1][row][k][l]
                 + sred[2][row][k][l] + sred[3][row][k][l] + bv;
        fpl[row * W + px] = 1.0 + 1.0 / (1.0 + exp(-s));
    }
}

// ---------------------------------------------------------------------------
// Selection. block = one (b,y) row; 256 threads = 64 float4-cols x 4 channel
// groups. f-row values live in registers, reused over 16 channels.
// ---------------------------------------------------------------------------
__global__ __launch_bounds__(256) void select_kernel(
    const float*  __restrict__ x0,
    const float*  __restrict__ x1,
    const double* __restrict__ f0,
    const double* __restrict__ f1,
    float* __restrict__ out,
    unsigned int* __restrict__ count1)
{
    const int by = blockIdx.x;        // 0 .. B*H-1
    const int b  = by >> 8;
    const int y  = by & (H - 1);
    const int tx = threadIdx.x & 63;
    const int tc = threadIdx.x >> 6;

    const size_t plane = (size_t)b * H * W + (size_t)y * W + (size_t)tx * 4;
    double g0[4], g1[4];
    #pragma unroll
    for (int j = 0; j < 4; ++j) { g0[j] = f0[plane + j]; g1[j] = f1[plane + j]; }

    const size_t rowbase = (size_t)b * C * H * W + (size_t)y * W + (size_t)tx * 4;

    unsigned int cnt = 0;
    for (int ci = tc; ci < C; ci += 4) {
        size_t off = rowbase + (size_t)ci * H * W;
        float4 a  = *(const float4*)(x0 + off);
        float4 bb = *(const float4*)(x1 + off);
        float4 r;
        { double w0=(double)a.x*g0[0], w1=(double)bb.x*g1[0]; bool s1=(w1>w0); cnt+=s1; r.x=s1?bb.x:a.x; }
        { double w0=(double)a.y*g0[1], w1=(double)bb.y*g1[1]; bool s1=(w1>w0); cnt+=s1; r.y=s1?bb.y:a.y; }
        { double w0=(double)a.z*g0[2], w1=(double)bb.z*g1[2]; bool s1=(w1>w0); cnt+=s1; r.z=s1?bb.z:a.z; }
        { double w0=(double)a.w*g0[3], w1=(double)bb.w*g1[3]; bool s1=(w1>w0); cnt+=s1; r.w=s1?bb.w:a.w; }
        *(float4*)(out + off) = r;
    }

    __shared__ unsigned int blk;
    if (threadIdx.x == 0) blk = 0;
    __syncthreads();
    atomicAdd(&blk, cnt);
    __syncthreads();
    if (threadIdx.x == 0) atomicAdd(count1, blk);
}

__global__ void finalize_kernel(const unsigned int* __restrict__ count1,
                                float* __restrict__ out_p)
{
    const double N = (double)B * C * H * W;
    double c1 = (double)(*count1);
    out_p[0] = (float)((N - c1) / N);
    out_p[1] = (float)(c1 / N);
}

extern "C" void kernel_launch(void* const* d_in, const int* in_sizes, int n_in,
                              void* d_out, int out_size, void* d_ws, size_t ws_size,
                              hipStream_t stream) {
    const float* x0    = (const float*)d_in[0];
    const float* x1    = (const float*)d_in[1];
    const float* dw_w0 = (const float*)d_in[2];
    const float* dw_b0 = (const float*)d_in[3];
    const float* pw_w0 = (const float*)d_in[4];
    const float* pw_b0 = (const float*)d_in[5];
    const float* dw_w1 = (const float*)d_in[6];
    const float* dw_b1 = (const float*)d_in[7];
    const float* pw_w1 = (const float*)d_in[8];
    const float* pw_b1 = (const float*)d_in[9];
    float* out = (float*)d_out;

    unsigned int* cnt  = (unsigned int*)d_ws;
    double*       wc   = (double*)((char*)d_ws + OFF_WC);
    double*       bias = (double*)((char*)d_ws + OFF_BIAS);
    double*       f    = (double*)((char*)d_ws + OFF_F);
    double*       f0   = f;                       // planes 0..7  (input 0)
    double*       f1   = f + (size_t)8 * PSZ;     // planes 8..15 (input 1)

    (void)hipMemsetAsync(d_ws, 0, 256, stream);

    prep_kernel<<<1, 128, 0, stream>>>(dw_w0, dw_b0, pw_w0, pw_b0,
                                       dw_w1, dw_b1, pw_w1, pw_b1, wc, bias);

    score2row_kernel<<<NPLANE * (H / 2), 256, 0, stream>>>(x0, x1, wc, bias, f);

    select_kernel<<<B * H, 256, 0, stream>>>(x0, x1, f0, f1, out, cnt);

    finalize_kernel<<<1, 1, 0, stream>>>(cnt, out + (size_t)B * C * H * W);
}